// Round 1
// baseline (1455.222 us; speedup 1.0000x reference)
//
#include <hip/hip_runtime.h>

#define B 8
#define F 257
#define C 8
#define T 800
#define TAPS 5
#define DELAY 3
#define K 40         // TAPS*C
#define NCOL 48      // K + C
#define T0 7         // DELAY + TAPS - 1
#define BF (B*F)     // 2056
#define PADT 801     // padded LDS time stride (odd -> banks spread)

// ---------------- kernel 1: inverse power weights ----------------
__global__ __launch_bounds__(256) void power_kernel(const float* __restrict__ sr,
                                                    const float* __restrict__ si,
                                                    float* __restrict__ W) {
    int bf = blockIdx.x;
    const float* srp = sr + (size_t)bf * C * T;
    const float* sip = si + (size_t)bf * C * T;
    for (int t = threadIdx.x; t < T; t += 256) {
        float s = 0.f;
#pragma unroll
        for (int c = 0; c < C; ++c) {
            float a = srp[c * T + t], b2 = sip[c * T + t];
            s += a * a + b2 * b2;
        }
        s *= (1.0f / C);
        s = fmaxf(s, 1e-7f);
        W[(size_t)bf * T + t] = 1.0f / s;
    }
}

// ---------------- kernel 2: R (40x40) and P (40x8) ----------------
#define CMAC(acc, a, b)                          \
    do {                                         \
        acc.x += a.x * b.x + a.y * b.y;          \
        acc.y += a.y * b.x - a.x * b.y;          \
    } while (0)

__global__ __launch_bounds__(256) void rp_kernel(const float* __restrict__ mr,
                                                 const float* __restrict__ mi,
                                                 const float* __restrict__ W,
                                                 float2* __restrict__ Rout,
                                                 float2* __restrict__ Pout) {
    __shared__ float2 Ysh[C][PADT];
    __shared__ float wsh[T];
    int bf = blockIdx.x;
    int tid = threadIdx.x;
    const float* mrp = mr + (size_t)bf * C * T;
    const float* mip = mi + (size_t)bf * C * T;
#pragma unroll
    for (int c = 0; c < C; ++c)
        for (int t = tid; t < T; t += 256)
            Ysh[c][t] = make_float2(mrp[c * T + t], mip[c * T + t]);
    for (int t = tid; t < T; t += 256)
        wsh[t] = W[(size_t)bf * T + t];
    __syncthreads();

    int tx = tid & 15, ty = tid >> 4;
    int r0 = tx, r1 = tx + 16;
    bool r2v = (tx + 32) < K;
    int r2 = r2v ? (tx + 32) : tx;

    const float2* Yf = &Ysh[0][0];
    // row a = k*C + c reads Y[c][t - DELAY - k], weighted by w[t]
    int rb0 = (r0 & 7) * PADT - DELAY - (r0 >> 3);
    int rb1 = (r1 & 7) * PADT - DELAY - (r1 >> 3);
    int rb2 = (r2 & 7) * PADT - DELAY - (r2 >> 3);
    int n0 = ty, n1 = ty + 16, n2 = ty + 32;
    // col n<K: conj(Yt[n,t]); col>=K: conj(Y[n-K][t])
    int cb0 = (n0 < K) ? ((n0 & 7) * PADT - DELAY - (n0 >> 3)) : ((n0 - K) * PADT);
    int cb1 = (n1 < K) ? ((n1 & 7) * PADT - DELAY - (n1 >> 3)) : ((n1 - K) * PADT);
    int cb2 = (n2 < K) ? ((n2 & 7) * PADT - DELAY - (n2 >> 3)) : ((n2 - K) * PADT);

    float2 acc[3][3];
#pragma unroll
    for (int i = 0; i < 3; ++i)
#pragma unroll
        for (int j = 0; j < 3; ++j)
            acc[i][j] = make_float2(0.f, 0.f);

#pragma unroll 2
    for (int t = T0; t < T; ++t) {
        float wt = wsh[t];
        float2 a0 = Yf[rb0 + t];
        float2 a1 = Yf[rb1 + t];
        float2 a2 = Yf[rb2 + t];
        float2 b0 = Yf[cb0 + t];
        float2 b1 = Yf[cb1 + t];
        float2 b2 = Yf[cb2 + t];
        a0.x *= wt; a0.y *= wt;
        a1.x *= wt; a1.y *= wt;
        a2.x *= wt; a2.y *= wt;
        CMAC(acc[0][0], a0, b0); CMAC(acc[0][1], a0, b1); CMAC(acc[0][2], a0, b2);
        CMAC(acc[1][0], a1, b0); CMAC(acc[1][1], a1, b1); CMAC(acc[1][2], a1, b2);
        CMAC(acc[2][0], a2, b0); CMAC(acc[2][1], a2, b1); CMAC(acc[2][2], a2, b2);
    }

    int rows[3] = {r0, r1, r2};
    bool rvalid[3] = {true, true, r2v};
    int cols[3] = {n0, n1, n2};
#pragma unroll
    for (int i = 0; i < 3; ++i) {
        if (!rvalid[i]) continue;
#pragma unroll
        for (int j = 0; j < 3; ++j) {
            int r = rows[i], n = cols[j];
            if (n < K)
                Rout[(size_t)bf * K * K + r * K + n] = acc[i][j];
            else
                Pout[(size_t)bf * K * C + r * C + (n - K)] = acc[i][j];
        }
    }
}

// ---------------- kernel 3: solve R G = P (complex LU, partial pivot) ----------------
__global__ __launch_bounds__(64) void solve_kernel(const float2* __restrict__ Rin,
                                                   const float2* __restrict__ Pin,
                                                   float2* __restrict__ Gout) {
    __shared__ float2 aug[K][NCOL + 1];  // pad to 49 to spread banks
    int bf = blockIdx.x;
    int lane = threadIdx.x;

    for (int i = lane; i < K * K; i += 64) {
        int r = i / K, c2 = i % K;
        float2 v = Rin[(size_t)bf * K * K + i];
        if (r == c2) v.x += 1e-10f;
        aug[r][c2] = v;
    }
    for (int i = lane; i < K * C; i += 64)
        aug[i >> 3][K + (i & 7)] = Pin[(size_t)bf * K * C + i];
    __syncthreads();

    // forward elimination with partial pivoting
    for (int j = 0; j < K; ++j) {
        float mag = -1.0f;
        int idx = lane;
        if (lane < K && lane >= j) {
            float2 v = aug[lane][j];
            mag = fabsf(v.x) + fabsf(v.y);
        }
        for (int off = 32; off; off >>= 1) {
            float om = __shfl_xor(mag, off);
            int oi = __shfl_xor(idx, off);
            if (om > mag || (om == mag && oi < idx)) { mag = om; idx = oi; }
        }
        int piv = idx;
        if (piv != j && lane < NCOL) {
            float2 tmp = aug[j][lane];
            aug[j][lane] = aug[piv][lane];
            aug[piv][lane] = tmp;
        }
        __syncthreads();
        float2 d = aug[j][j];
        float den = d.x * d.x + d.y * d.y;
        float2 invp = make_float2(d.x / den, -d.y / den);
        if (lane > j && lane < K) {
            float2 v = aug[lane][j];
            float2 l = make_float2(v.x * invp.x - v.y * invp.y,
                                   v.x * invp.y + v.y * invp.x);
            for (int n = j + 1; n < NCOL; ++n) {
                float2 u = aug[j][n];
                float2 a = aug[lane][n];
                a.x -= l.x * u.x - l.y * u.y;
                a.y -= l.x * u.y + l.y * u.x;
                aug[lane][n] = a;
            }
            aug[lane][j] = l;
        }
        __syncthreads();
    }

    // upward substitution on RHS columns
    for (int j = K - 1; j >= 0; --j) {
        float2 d = aug[j][j];
        float den = d.x * d.x + d.y * d.y;
        float2 invp = make_float2(d.x / den, -d.y / den);
        if (lane < C) {
            float2 v = aug[j][K + lane];
            aug[j][K + lane] = make_float2(v.x * invp.x - v.y * invp.y,
                                           v.x * invp.y + v.y * invp.x);
        }
        __syncthreads();
        for (int id = lane; id < j * C; id += 64) {
            int i = id >> 3, e = id & 7;
            float2 u = aug[i][j];
            float2 x = aug[j][K + e];
            float2 a = aug[i][K + e];
            a.x -= u.x * x.x - u.y * x.y;
            a.y -= u.x * x.y + u.y * x.x;
            aug[i][K + e] = a;
        }
        __syncthreads();
    }

    for (int i = lane; i < K * C; i += 64)
        Gout[(size_t)bf * K * C + i] = aug[i >> 3][K + (i & 7)];
}

// ---------------- kernel 4: X = Y - G^H Yt, mask, write out ----------------
__global__ __launch_bounds__(256) void x_kernel(const float* __restrict__ mr,
                                                const float* __restrict__ mi,
                                                const float2* __restrict__ Gin,
                                                const int* __restrict__ ilens,
                                                float2* __restrict__ out) {
    __shared__ float2 Ysh[C][PADT];
    __shared__ float2 Gsh[K][C];
    int bf = blockIdx.x;
    int b = bf / F;
    int tid = threadIdx.x;
    const float* mrp = mr + (size_t)bf * C * T;
    const float* mip = mi + (size_t)bf * C * T;
#pragma unroll
    for (int c = 0; c < C; ++c)
        for (int t = tid; t < T; t += 256)
            Ysh[c][t] = make_float2(mrp[c * T + t], mip[c * T + t]);
    for (int i = tid; i < K * C; i += 256)
        Gsh[i >> 3][i & 7] = Gin[(size_t)bf * K * C + i];
    __syncthreads();

    int len = ilens[b];
    for (int t = tid; t < T; t += 256) {
        float2 acc[C];
        if (t < len) {
#pragma unroll
            for (int e = 0; e < C; ++e) acc[e] = Ysh[e][t];
#pragma unroll
            for (int k = 0; k < TAPS; ++k) {
                int ts = t - DELAY - k;
                if (ts >= 0) {
#pragma unroll
                    for (int c = 0; c < C; ++c) {
                        float2 yt = Ysh[c][ts];
                        int a = k * C + c;
#pragma unroll
                        for (int e = 0; e < C; ++e) {
                            float2 g = Gsh[a][e];
                            // acc[e] -= conj(g) * yt
                            acc[e].x -= g.x * yt.x + g.y * yt.y;
                            acc[e].y -= g.x * yt.y - g.y * yt.x;
                        }
                    }
                }
            }
        } else {
#pragma unroll
            for (int e = 0; e < C; ++e) acc[e] = make_float2(0.f, 0.f);
        }
#pragma unroll
        for (int e = 0; e < C; ++e)
            out[((size_t)bf * C + e) * T + t] = acc[e];
    }
}

extern "C" void kernel_launch(void* const* d_in, const int* in_sizes, int n_in,
                              void* d_out, int out_size, void* d_ws, size_t ws_size,
                              hipStream_t stream) {
    const float* sep_r = (const float*)d_in[0];
    const float* sep_i = (const float*)d_in[1];
    const float* mix_r = (const float*)d_in[2];
    const float* mix_i = (const float*)d_in[3];
    const int* ilens   = (const int*)d_in[4];

    float* ws = (float*)d_ws;
    float* W = ws;                                        // BF*T floats
    float2* Rws = (float2*)(ws + (size_t)BF * T);         // BF*K*K float2
    float2* Gws = Rws + (size_t)BF * K * K;               // BF*K*C float2 (P then G in-place)

    power_kernel<<<BF, 256, 0, stream>>>(sep_r, sep_i, W);
    rp_kernel<<<BF, 256, 0, stream>>>(mix_r, mix_i, W, Rws, Gws);
    solve_kernel<<<BF, 64, 0, stream>>>(Rws, Gws, Gws);
    x_kernel<<<BF, 256, 0, stream>>>(mix_r, mix_i, Gws, ilens, (float2*)d_out);
}

// Round 3
// 772.881 us; speedup vs baseline: 1.8829x; 1.8829x over previous
//
#include <hip/hip_runtime.h>

#define B 8
#define F 257
#define C 8
#define T 800
#define TAPS 5
#define DELAY 3
#define K 40         // TAPS*C
#define NCOL 48      // K + C
#define T0 7         // DELAY + TAPS - 1
#define BF (B*F)     // 2056

// rp chunking
#define TC 200
#define HALO 7
#define LSTR 209     // LDS row stride in float2 (418 dwords === 2 mod 32 -> <=2-way conflicts)

// ---------------- kernel 1: inverse power weights ----------------
__global__ __launch_bounds__(256) void power_kernel(const float* __restrict__ sr,
                                                    const float* __restrict__ si,
                                                    float* __restrict__ W) {
    int bf = blockIdx.x;
    const float* srp = sr + (size_t)bf * C * T;
    const float* sip = si + (size_t)bf * C * T;
    for (int t = threadIdx.x; t < T; t += 256) {
        float s = 0.f;
#pragma unroll
        for (int c = 0; c < C; ++c) {
            float a = srp[c * T + t], b2 = sip[c * T + t];
            s = fmaf(a, a, s);
            s = fmaf(b2, b2, s);
        }
        s *= (1.0f / C);
        s = fmaxf(s, 1e-7f);
        W[(size_t)bf * T + t] = 1.0f / s;
    }
}

// 4 guaranteed FMAs per complex MAC: acc += a * conj(b)
#define CMACW(acc, a, b)                         \
    do {                                         \
        acc.x = fmaf(a.x, b.x, acc.x);           \
        acc.x = fmaf(a.y, b.y, acc.x);           \
        acc.y = fmaf(a.y, b.x, acc.y);           \
        acc.y = fmaf(-a.x, b.y, acc.y);          \
    } while (0)

// ---------------- kernel 2: R (40x40) and P (40x8), time-chunked ----------------
__global__ __launch_bounds__(256) void rp_kernel(const float* __restrict__ mr,
                                                 const float* __restrict__ mi,
                                                 const float* __restrict__ W,
                                                 float2* __restrict__ Rout,
                                                 float2* __restrict__ Pout) {
    __shared__ float2 Ysh[C * LSTR];   // covers t in [ts-7, ts+TC)
    __shared__ float wsh[TC];
    int bf = blockIdx.x;
    int tid = threadIdx.x;
    const float* mrp = mr + (size_t)bf * C * T;
    const float* mip = mi + (size_t)bf * C * T;
    const float* Wp = W + (size_t)bf * T;

    int tx = tid & 15, ty = tid >> 4;
    int r0 = tx, r1 = tx + 16;
    bool r2v = (tx + 32) < K;
    int r2 = r2v ? (tx + 32) : tx;
    int n0 = ty, n1 = ty + 16, n2 = ty + 32;

    // LDS index for row a=k*C+c at loop var la (la = t - ts + HALO):
    //   (a&7)*LSTR + la - DELAY - (a>>3)
    int oa0 = (r0 & 7) * LSTR - DELAY - (r0 >> 3);
    int oa1 = (r1 & 7) * LSTR - DELAY - (r1 >> 3);
    int oa2 = (r2 & 7) * LSTR - DELAY - (r2 >> 3);
    // col n<K: conj(Yt[n,t]); col>=K: conj(Y[n-K][t]).  n0,n1 always < K.
    int ob0 = (n0 & 7) * LSTR - DELAY - (n0 >> 3);
    int ob1 = (n1 & 7) * LSTR - DELAY - (n1 >> 3);
    int ob2 = (n2 < K) ? ((n2 & 7) * LSTR - DELAY - (n2 >> 3)) : ((n2 - K) * LSTR);

    float2 acc[3][3];
#pragma unroll
    for (int i = 0; i < 3; ++i)
#pragma unroll
        for (int j = 0; j < 3; ++j)
            acc[i][j] = make_float2(0.f, 0.f);

    for (int ch = 0; ch < T / TC; ++ch) {
        int ts = ch * TC;
        __syncthreads();   // protect previous chunk's reads
        // stage Y for t in [ts-7, ts+TC)
#pragma unroll
        for (int c = 0; c < C; ++c) {
            for (int l = tid; l < TC + HALO; l += 256) {
                int tg = ts - HALO + l;
                Ysh[c * LSTR + l] = (tg >= 0)
                    ? make_float2(mrp[c * T + tg], mip[c * T + tg])
                    : make_float2(0.f, 0.f);
            }
        }
        for (int l = tid; l < TC; l += 256)
            wsh[l] = Wp[ts + l];
        __syncthreads();

        int tbeg = (ch == 0) ? T0 : ts;
        int la = tbeg - ts + HALO;
        int nIter = ts + TC - tbeg;
#pragma unroll 4
        for (int q = 0; q < nIter; ++q, ++la) {
            float wt = wsh[la - HALO];
            float2 a0 = Ysh[oa0 + la];
            float2 a1 = Ysh[oa1 + la];
            float2 a2 = Ysh[oa2 + la];
            float2 b0 = Ysh[ob0 + la];
            float2 b1 = Ysh[ob1 + la];
            float2 b2 = Ysh[ob2 + la];
            float2 aw0 = make_float2(a0.x * wt, a0.y * wt);
            float2 aw1 = make_float2(a1.x * wt, a1.y * wt);
            float2 aw2 = make_float2(a2.x * wt, a2.y * wt);
            CMACW(acc[0][0], aw0, b0); CMACW(acc[0][1], aw0, b1); CMACW(acc[0][2], aw0, b2);
            CMACW(acc[1][0], aw1, b0); CMACW(acc[1][1], aw1, b1); CMACW(acc[1][2], aw1, b2);
            CMACW(acc[2][0], aw2, b0); CMACW(acc[2][1], aw2, b1); CMACW(acc[2][2], aw2, b2);
        }
    }

    int rows[3] = {r0, r1, r2};
    bool rvalid[3] = {true, true, r2v};
    int cols[3] = {n0, n1, n2};
#pragma unroll
    for (int i = 0; i < 3; ++i) {
        if (!rvalid[i]) continue;
#pragma unroll
        for (int j = 0; j < 3; ++j) {
            int r = rows[i], n = cols[j];
            if (n < K)
                Rout[(size_t)bf * K * K + r * K + n] = acc[i][j];
            else
                Pout[(size_t)bf * K * C + r * C + (n - K)] = acc[i][j];
        }
    }
}

// ---------------- kernel 3: solve R G = P (complex LU, partial pivot) ----------------
__global__ __launch_bounds__(64) void solve_kernel(const float2* __restrict__ Rin,
                                                   const float2* __restrict__ Pin,
                                                   float2* __restrict__ Gout) {
    __shared__ float2 aug[K][NCOL + 1];  // pad to 49 to spread banks
    int bf = blockIdx.x;
    int lane = threadIdx.x;

    for (int i = lane; i < K * K; i += 64) {
        int r = i / K, c2 = i % K;
        float2 v = Rin[(size_t)bf * K * K + i];
        if (r == c2) v.x += 1e-10f;
        aug[r][c2] = v;
    }
    for (int i = lane; i < K * C; i += 64)
        aug[i >> 3][K + (i & 7)] = Pin[(size_t)bf * K * C + i];
    __syncthreads();

    // forward elimination with partial pivoting
    for (int j = 0; j < K; ++j) {
        float mag = -1.0f;
        int idx = lane;
        if (lane < K && lane >= j) {
            float2 v = aug[lane][j];
            mag = fabsf(v.x) + fabsf(v.y);
        }
        for (int off = 32; off; off >>= 1) {
            float om = __shfl_xor(mag, off);
            int oi = __shfl_xor(idx, off);
            if (om > mag || (om == mag && oi < idx)) { mag = om; idx = oi; }
        }
        int piv = idx;
        if (piv != j && lane < NCOL) {
            float2 tmp = aug[j][lane];
            aug[j][lane] = aug[piv][lane];
            aug[piv][lane] = tmp;
        }
        __syncthreads();
        float2 d = aug[j][j];
        float den = d.x * d.x + d.y * d.y;
        float2 invp = make_float2(d.x / den, -d.y / den);
        if (lane > j && lane < K) {
            float2 v = aug[lane][j];
            float2 l = make_float2(v.x * invp.x - v.y * invp.y,
                                   v.x * invp.y + v.y * invp.x);
            for (int n = j + 1; n < NCOL; ++n) {
                float2 u = aug[j][n];
                float2 a = aug[lane][n];
                a.x -= l.x * u.x - l.y * u.y;
                a.y -= l.x * u.y + l.y * u.x;
                aug[lane][n] = a;
            }
            aug[lane][j] = l;
        }
        __syncthreads();
    }

    // upward substitution on RHS columns
    for (int j = K - 1; j >= 0; --j) {
        float2 d = aug[j][j];
        float den = d.x * d.x + d.y * d.y;
        float2 invp = make_float2(d.x / den, -d.y / den);
        if (lane < C) {
            float2 v = aug[j][K + lane];
            aug[j][K + lane] = make_float2(v.x * invp.x - v.y * invp.y,
                                           v.x * invp.y + v.y * invp.x);
        }
        __syncthreads();
        for (int id = lane; id < j * C; id += 64) {
            int i = id >> 3, e = id & 7;
            float2 u = aug[i][j];
            float2 x = aug[j][K + e];
            float2 a = aug[i][K + e];
            a.x -= u.x * x.x - u.y * x.y;
            a.y -= u.x * x.y + u.y * x.x;
            aug[i][K + e] = a;
        }
        __syncthreads();
    }

    for (int i = lane; i < K * C; i += 64)
        Gout[(size_t)bf * K * C + i] = aug[i >> 3][K + (i & 7)];
}

// ---------------- kernel 4: X = Y - G^H Yt, mask, write out ----------------
// a-outer structure: G row held in registers, amortized over 4 t-columns/thread.
#define PADT 801
__global__ __launch_bounds__(256) void x_kernel(const float* __restrict__ mr,
                                                const float* __restrict__ mi,
                                                const float2* __restrict__ Gin,
                                                const int* __restrict__ ilens,
                                                float2* __restrict__ out) {
    __shared__ float2 Ysh[C][PADT];
    __shared__ float2 Gsh[K][C];
    int bf = blockIdx.x;
    int b = bf / F;
    int tid = threadIdx.x;
    const float* mrp = mr + (size_t)bf * C * T;
    const float* mip = mi + (size_t)bf * C * T;
#pragma unroll
    for (int c = 0; c < C; ++c)
        for (int t = tid; t < T; t += 256)
            Ysh[c][t] = make_float2(mrp[c * T + t], mip[c * T + t]);
    for (int i = tid; i < K * C; i += 256)
        Gsh[i >> 3][i & 7] = Gin[(size_t)bf * K * C + i];
    __syncthreads();

    int len = ilens[b];

    float2 acc[4][C];
#pragma unroll
    for (int it = 0; it < 4; ++it) {
        int t = tid + it * 256;
#pragma unroll
        for (int e = 0; e < C; ++e)
            acc[it][e] = (t < T) ? Ysh[e][t] : make_float2(0.f, 0.f);
    }

#pragma unroll
    for (int k = 0; k < TAPS; ++k) {
#pragma unroll
        for (int c = 0; c < C; ++c) {
            int a = k * C + c;
            float2 g[C];
#pragma unroll
            for (int e = 0; e < C; ++e) g[e] = Gsh[a][e];
#pragma unroll
            for (int it = 0; it < 4; ++it) {
                int t = tid + it * 256;
                int tsrc = t - DELAY - k;
                if (t < T && tsrc >= 0) {
                    float2 yt = Ysh[c][tsrc];
#pragma unroll
                    for (int e = 0; e < C; ++e) {
                        // acc -= conj(g) * yt
                        acc[it][e].x = fmaf(-g[e].x, yt.x, acc[it][e].x);
                        acc[it][e].x = fmaf(-g[e].y, yt.y, acc[it][e].x);
                        acc[it][e].y = fmaf(-g[e].x, yt.y, acc[it][e].y);
                        acc[it][e].y = fmaf(g[e].y, yt.x, acc[it][e].y);
                    }
                }
            }
        }
    }

#pragma unroll
    for (int it = 0; it < 4; ++it) {
        int t = tid + it * 256;
        if (t < T) {
            bool ok = (t < len);
#pragma unroll
            for (int e = 0; e < C; ++e) {
                float2 v = ok ? acc[it][e] : make_float2(0.f, 0.f);
                out[((size_t)bf * C + e) * T + t] = v;
            }
        }
    }
}

extern "C" void kernel_launch(void* const* d_in, const int* in_sizes, int n_in,
                              void* d_out, int out_size, void* d_ws, size_t ws_size,
                              hipStream_t stream) {
    const float* sep_r = (const float*)d_in[0];
    const float* sep_i = (const float*)d_in[1];
    const float* mix_r = (const float*)d_in[2];
    const float* mix_i = (const float*)d_in[3];
    const int* ilens   = (const int*)d_in[4];

    float* ws = (float*)d_ws;
    float* W = ws;                                        // BF*T floats
    float2* Rws = (float2*)(ws + (size_t)BF * T);         // BF*K*K float2
    float2* Gws = Rws + (size_t)BF * K * K;               // BF*K*C float2 (P then G in-place)

    power_kernel<<<BF, 256, 0, stream>>>(sep_r, sep_i, W);
    rp_kernel<<<BF, 256, 0, stream>>>(mix_r, mix_i, W, Rws, Gws);
    solve_kernel<<<BF, 64, 0, stream>>>(Rws, Gws, Gws);
    x_kernel<<<BF, 256, 0, stream>>>(mix_r, mix_i, Gws, ilens, (float2*)d_out);
}

// Round 4
// 589.758 us; speedup vs baseline: 2.4675x; 1.3105x over previous
//
#include <hip/hip_runtime.h>

#define B 8
#define F 257
#define C 8
#define T 800
#define TAPS 5
#define DELAY 3
#define K 40         // TAPS*C
#define NCOL 48      // K + C
#define T0 7         // DELAY + TAPS - 1
#define BF (B*F)     // 2056

// rp window-kernel geometry
#define TQ 200       // t-range per wave (4 waves x 200 = 800), multiple of 8
#define TCW 104      // chunk length (multiple of 8)
#define ROWF2 113    // LDS row stride in float2 (113 mod 16 == 1 -> conflict-free b64 reads)
#define WREG 960     // float2 per wave region (8*113=904 Y + 52 w + pad)

// ---------------- kernel 1: inverse power weights ----------------
__global__ __launch_bounds__(256) void power_kernel(const float* __restrict__ sr,
                                                    const float* __restrict__ si,
                                                    float* __restrict__ W) {
    int bf = blockIdx.x;
    const float* srp = sr + (size_t)bf * C * T;
    const float* sip = si + (size_t)bf * C * T;
    for (int t = threadIdx.x; t < T; t += 256) {
        float s = 0.f;
#pragma unroll
        for (int c = 0; c < C; ++c) {
            float a = srp[c * T + t], b2 = sip[c * T + t];
            s = fmaf(a, a, s);
            s = fmaf(b2, b2, s);
        }
        s *= (1.0f / C);
        s = fmaxf(s, 1e-7f);
        W[(size_t)bf * T + t] = 1.0f / s;
    }
}

// ---------------- kernel 2: R (40x40) and P (40x8) via sliding windows ----------------
// Block = 256 thr = 4 waves, all on ONE bf. Wave w sums t in [w*200, w*200+200).
// Lane owns channel pair (c_row = lane>>3, c_col = lane&7), computes 5x5 tap block of R
// plus 5 taps of P. Operands live in two 8-deep register windows; 2 LDS b64 reads per t.
__global__ __launch_bounds__(256) void rp_kernel(const float* __restrict__ mr,
                                                 const float* __restrict__ mi,
                                                 const float* __restrict__ W,
                                                 float2* __restrict__ Rout,
                                                 float2* __restrict__ Pout) {
    __shared__ float2 SH[4 * WREG];  // 30720 B
    const int bf = blockIdx.x;
    const int tid = threadIdx.x;
    const int lane = tid & 63;
    const int wid = tid >> 6;
    const int c_col = lane & 7;
    const int c_row = lane >> 3;

    const float* mrp = mr + (size_t)bf * C * T;
    const float* mip = mi + (size_t)bf * C * T;
    const float* Wp = W + (size_t)bf * T;

    float2* Yw = SH + wid * WREG;
    float* wv = (float*)(Yw + 8 * ROWF2);
    const float2* Yr = Yw + c_row * ROWF2;
    const float2* Yc = Yw + c_col * ROWF2;

    float2 acc[5][5];
    float2 accP[5];
#pragma unroll
    for (int j = 0; j < 5; ++j) {
#pragma unroll
        for (int kc = 0; kc < 5; ++kc) acc[j][kc] = make_float2(0.f, 0.f);
        accP[j] = make_float2(0.f, 0.f);
    }

    const int tbase = wid * TQ;
#pragma unroll
    for (int ch = 0; ch < 2; ++ch) {
        const int ts = tbase + ch * TCW;          // 0 or 104 offset; multiple of 8
        const int len = ch ? (TQ - TCW) : TCW;    // 104 then 96

        // make sure previous chunk's reads are done before overwriting (wave-lockstep)
        __builtin_amdgcn_sched_barrier(0);
        asm volatile("s_waitcnt lgkmcnt(0)" ::: "memory");
        __builtin_amdgcn_sched_barrier(0);

        // stage Y[c][ts-8 .. ts+103] (112 entries per row) and weights
#pragma unroll
        for (int c = 0; c < 8; ++c) {
#pragma unroll
            for (int rep = 0; rep < 2; ++rep) {
                int l = lane + rep * 64;
                if (l < TCW + 8) {
                    int t = ts - 8 + l;
                    float2 v = make_float2(0.f, 0.f);
                    if (t >= 0 && t < T) v = make_float2(mrp[c * T + t], mip[c * T + t]);
                    Yw[c * ROWF2 + l] = v;
                }
            }
        }
#pragma unroll
        for (int rep = 0; rep < 2; ++rep) {
            int l = lane + rep * 64;
            if (l < TCW) {
                int t = ts + l;
                wv[l] = (t >= T0 && t < T) ? Wp[t] : 0.f;
            }
        }
        __builtin_amdgcn_sched_barrier(0);
        asm volatile("s_waitcnt lgkmcnt(0)" ::: "memory");
        __builtin_amdgcn_sched_barrier(0);

        // prime windows with y[ts-8 .. ts-1]; slot m holds t' === m (mod 8)
        float2 wr[8], wc[8];
#pragma unroll
        for (int m = 0; m < 8; ++m) { wr[m] = Yr[m]; wc[m] = Yc[m]; }

        for (int ug = 0; ug < len; ug += 8) {
            const float2* Yru = Yr + 8 + ug;
            const float2* Ycu = Yc + 8 + ug;
            const float* wvu = wv + ug;
#pragma unroll
            for (int p = 0; p < 8; ++p) {
                float wt = wvu[p];
                wr[p] = Yru[p];   // y_row[t], slot p = t&7
                wc[p] = Ycu[p];   // y_col[t]
                float2 aw[5];
#pragma unroll
                for (int j = 0; j < 5; ++j) {
                    float2 a = wr[(p + 5 - j) & 7];   // y_row[t-3-j], never slot p
                    aw[j].x = a.x * wt;
                    aw[j].y = a.y * wt;
                }
#pragma unroll
                for (int j = 0; j < 5; ++j) {
#pragma unroll
                    for (int kc = 0; kc < 5; ++kc) {
                        float2 b = wc[(p + 5 - kc) & 7];  // y_col[t-3-kc]
                        acc[j][kc].x = fmaf(aw[j].x, b.x, acc[j][kc].x);
                        acc[j][kc].x = fmaf(aw[j].y, b.y, acc[j][kc].x);
                        acc[j][kc].y = fmaf(aw[j].y, b.x, acc[j][kc].y);
                        acc[j][kc].y = fmaf(-aw[j].x, b.y, acc[j][kc].y);
                    }
                    float2 b0 = wc[p];                     // y_col[t] for P
                    accP[j].x = fmaf(aw[j].x, b0.x, accP[j].x);
                    accP[j].x = fmaf(aw[j].y, b0.y, accP[j].x);
                    accP[j].y = fmaf(aw[j].y, b0.x, accP[j].y);
                    accP[j].y = fmaf(-aw[j].x, b0.y, accP[j].y);
                }
            }
        }
    }

    // ---- cross-wave reduction (tree): 30 float2 per lane ----
    __syncthreads();
    if (wid == 1 || wid == 3) {
        float2* dst = SH + (wid >> 1) * 1920;
#pragma unroll
        for (int j = 0; j < 5; ++j)
#pragma unroll
            for (int kc = 0; kc < 5; ++kc)
                dst[(j * 5 + kc) * 64 + lane] = acc[j][kc];
#pragma unroll
        for (int j = 0; j < 5; ++j)
            dst[(25 + j) * 64 + lane] = accP[j];
    }
    __syncthreads();
    if ((wid & 1) == 0) {
        const float2* src = SH + (wid >> 1) * 1920;
#pragma unroll
        for (int j = 0; j < 5; ++j)
#pragma unroll
            for (int kc = 0; kc < 5; ++kc) {
                float2 v = src[(j * 5 + kc) * 64 + lane];
                acc[j][kc].x += v.x; acc[j][kc].y += v.y;
            }
#pragma unroll
        for (int j = 0; j < 5; ++j) {
            float2 v = src[(25 + j) * 64 + lane];
            accP[j].x += v.x; accP[j].y += v.y;
        }
    }
    __syncthreads();
    if (wid == 2) {
        float2* dst = SH;
#pragma unroll
        for (int j = 0; j < 5; ++j)
#pragma unroll
            for (int kc = 0; kc < 5; ++kc)
                dst[(j * 5 + kc) * 64 + lane] = acc[j][kc];
#pragma unroll
        for (int j = 0; j < 5; ++j)
            dst[(25 + j) * 64 + lane] = accP[j];
    }
    __syncthreads();
    if (wid == 0) {
        const float2* src = SH;
        float2* Rp = Rout + (size_t)bf * K * K;
        float2* Pp = Pout + (size_t)bf * K * C;
#pragma unroll
        for (int j = 0; j < 5; ++j) {
#pragma unroll
            for (int kc = 0; kc < 5; ++kc) {
                float2 v = src[(j * 5 + kc) * 64 + lane];
                v.x += acc[j][kc].x; v.y += acc[j][kc].y;
                Rp[(j * 8 + c_row) * K + kc * 8 + c_col] = v;
            }
            float2 v = src[(25 + j) * 64 + lane];
            v.x += accP[j].x; v.y += accP[j].y;
            Pp[(j * 8 + c_row) * C + c_col] = v;
        }
    }
}

// ---------------- kernel 3: solve R G = P (complex LU, partial pivot) ----------------
__global__ __launch_bounds__(64) void solve_kernel(const float2* __restrict__ Rin,
                                                   const float2* __restrict__ Pin,
                                                   float2* __restrict__ Gout) {
    __shared__ float2 aug[K][NCOL + 1];  // pad to 49 to spread banks
    int bf = blockIdx.x;
    int lane = threadIdx.x;

    for (int i = lane; i < K * K; i += 64) {
        int r = i / K, c2 = i % K;
        float2 v = Rin[(size_t)bf * K * K + i];
        if (r == c2) v.x += 1e-10f;
        aug[r][c2] = v;
    }
    for (int i = lane; i < K * C; i += 64)
        aug[i >> 3][K + (i & 7)] = Pin[(size_t)bf * K * C + i];
    __syncthreads();

    // forward elimination with partial pivoting
    for (int j = 0; j < K; ++j) {
        float mag = -1.0f;
        int idx = lane;
        if (lane < K && lane >= j) {
            float2 v = aug[lane][j];
            mag = fabsf(v.x) + fabsf(v.y);
        }
        for (int off = 32; off; off >>= 1) {
            float om = __shfl_xor(mag, off);
            int oi = __shfl_xor(idx, off);
            if (om > mag || (om == mag && oi < idx)) { mag = om; idx = oi; }
        }
        int piv = idx;
        if (piv != j && lane < NCOL) {
            float2 tmp = aug[j][lane];
            aug[j][lane] = aug[piv][lane];
            aug[piv][lane] = tmp;
        }
        __syncthreads();
        float2 d = aug[j][j];
        float den = d.x * d.x + d.y * d.y;
        float2 invp = make_float2(d.x / den, -d.y / den);
        if (lane > j && lane < K) {
            float2 v = aug[lane][j];
            float2 l = make_float2(v.x * invp.x - v.y * invp.y,
                                   v.x * invp.y + v.y * invp.x);
            for (int n = j + 1; n < NCOL; ++n) {
                float2 u = aug[j][n];
                float2 a = aug[lane][n];
                a.x -= l.x * u.x - l.y * u.y;
                a.y -= l.x * u.y + l.y * u.x;
                aug[lane][n] = a;
            }
            aug[lane][j] = l;
        }
        __syncthreads();
    }

    // upward substitution on RHS columns
    for (int j = K - 1; j >= 0; --j) {
        float2 d = aug[j][j];
        float den = d.x * d.x + d.y * d.y;
        float2 invp = make_float2(d.x / den, -d.y / den);
        if (lane < C) {
            float2 v = aug[j][K + lane];
            aug[j][K + lane] = make_float2(v.x * invp.x - v.y * invp.y,
                                           v.x * invp.y + v.y * invp.x);
        }
        __syncthreads();
        for (int id = lane; id < j * C; id += 64) {
            int i = id >> 3, e = id & 7;
            float2 u = aug[i][j];
            float2 x = aug[j][K + e];
            float2 a = aug[i][K + e];
            a.x -= u.x * x.x - u.y * x.y;
            a.y -= u.x * x.y + u.y * x.x;
            aug[i][K + e] = a;
        }
        __syncthreads();
    }

    for (int i = lane; i < K * C; i += 64)
        Gout[(size_t)bf * K * C + i] = aug[i >> 3][K + (i & 7)];
}

// ---------------- kernel 4: X = Y - G^H Yt, mask, write out ----------------
#define PADT 801
__global__ __launch_bounds__(256) void x_kernel(const float* __restrict__ mr,
                                                const float* __restrict__ mi,
                                                const float2* __restrict__ Gin,
                                                const int* __restrict__ ilens,
                                                float2* __restrict__ out) {
    __shared__ float2 Ysh[C][PADT];
    __shared__ float2 Gsh[K][C];
    int bf = blockIdx.x;
    int b = bf / F;
    int tid = threadIdx.x;
    const float* mrp = mr + (size_t)bf * C * T;
    const float* mip = mi + (size_t)bf * C * T;
#pragma unroll
    for (int c = 0; c < C; ++c)
        for (int t = tid; t < T; t += 256)
            Ysh[c][t] = make_float2(mrp[c * T + t], mip[c * T + t]);
    for (int i = tid; i < K * C; i += 256)
        Gsh[i >> 3][i & 7] = Gin[(size_t)bf * K * C + i];
    __syncthreads();

    int len = ilens[b];

    float2 acc[4][C];
#pragma unroll
    for (int it = 0; it < 4; ++it) {
        int t = tid + it * 256;
#pragma unroll
        for (int e = 0; e < C; ++e)
            acc[it][e] = (t < T) ? Ysh[e][t] : make_float2(0.f, 0.f);
    }

#pragma unroll
    for (int k = 0; k < TAPS; ++k) {
#pragma unroll
        for (int c = 0; c < C; ++c) {
            int a = k * C + c;
            float2 g[C];
#pragma unroll
            for (int e = 0; e < C; ++e) g[e] = Gsh[a][e];
#pragma unroll
            for (int it = 0; it < 4; ++it) {
                int t = tid + it * 256;
                int tsrc = t - DELAY - k;
                if (t < T && tsrc >= 0) {
                    float2 yt = Ysh[c][tsrc];
#pragma unroll
                    for (int e = 0; e < C; ++e) {
                        acc[it][e].x = fmaf(-g[e].x, yt.x, acc[it][e].x);
                        acc[it][e].x = fmaf(-g[e].y, yt.y, acc[it][e].x);
                        acc[it][e].y = fmaf(-g[e].x, yt.y, acc[it][e].y);
                        acc[it][e].y = fmaf(g[e].y, yt.x, acc[it][e].y);
                    }
                }
            }
        }
    }

#pragma unroll
    for (int it = 0; it < 4; ++it) {
        int t = tid + it * 256;
        if (t < T) {
            bool ok = (t < len);
#pragma unroll
            for (int e = 0; e < C; ++e) {
                float2 v = ok ? acc[it][e] : make_float2(0.f, 0.f);
                out[((size_t)bf * C + e) * T + t] = v;
            }
        }
    }
}

extern "C" void kernel_launch(void* const* d_in, const int* in_sizes, int n_in,
                              void* d_out, int out_size, void* d_ws, size_t ws_size,
                              hipStream_t stream) {
    const float* sep_r = (const float*)d_in[0];
    const float* sep_i = (const float*)d_in[1];
    const float* mix_r = (const float*)d_in[2];
    const float* mix_i = (const float*)d_in[3];
    const int* ilens   = (const int*)d_in[4];

    float* ws = (float*)d_ws;
    float* W = ws;                                        // BF*T floats
    float2* Rws = (float2*)(ws + (size_t)BF * T);         // BF*K*K float2
    float2* Gws = Rws + (size_t)BF * K * K;               // BF*K*C float2 (P then G in-place)

    power_kernel<<<BF, 256, 0, stream>>>(sep_r, sep_i, W);
    rp_kernel<<<BF, 256, 0, stream>>>(mix_r, mix_i, W, Rws, Gws);
    solve_kernel<<<BF, 64, 0, stream>>>(Rws, Gws, Gws);
    x_kernel<<<BF, 256, 0, stream>>>(mix_r, mix_i, Gws, ilens, (float2*)d_out);
}

// Round 5
// 485.319 us; speedup vs baseline: 2.9985x; 1.2152x over previous
//
#include <hip/hip_runtime.h>

#define B 8
#define F 257
#define C 8
#define T 800
#define TAPS 5
#define DELAY 3
#define K 40         // TAPS*C
#define NCOL 48      // K + C
#define T0 7         // DELAY + TAPS - 1
#define BF (B*F)     // 2056

typedef __bf16 bf16x8 __attribute__((ext_vector_type(8)));
typedef __bf16 bf16x4 __attribute__((ext_vector_type(4)));
typedef float f32x4 __attribute__((ext_vector_type(4)));

// ---------------- kernel 1: inverse power weights (w=0 for t<T0) ----------------
__global__ __launch_bounds__(256) void power_kernel(const float* __restrict__ sr,
                                                    const float* __restrict__ si,
                                                    float* __restrict__ W) {
    int bf = blockIdx.x;
    const float* srp = sr + (size_t)bf * C * T;
    const float* sip = si + (size_t)bf * C * T;
    int t0 = threadIdx.x * 4;
    if (t0 < T) {
        float s[4] = {0.f, 0.f, 0.f, 0.f};
#pragma unroll
        for (int c = 0; c < C; ++c) {
            float4 a = *(const float4*)(srp + c * T + t0);
            float4 b = *(const float4*)(sip + c * T + t0);
            s[0] = fmaf(a.x, a.x, fmaf(b.x, b.x, s[0]));
            s[1] = fmaf(a.y, a.y, fmaf(b.y, b.y, s[1]));
            s[2] = fmaf(a.z, a.z, fmaf(b.z, b.z, s[2]));
            s[3] = fmaf(a.w, a.w, fmaf(b.w, b.w, s[3]));
        }
        float4 w;
        float* wp = (float*)&w;
#pragma unroll
        for (int e = 0; e < 4; ++e) {
            float v = fmaxf(s[e] * (1.0f / C), 1e-7f);
            wp[e] = (t0 + e < T0) ? 0.f : (1.0f / v);
        }
        *(float4*)(W + (size_t)bf * T + t0) = w;
    }
}

// ---------------- kernel 2: R (40x40) and P (40x8) via bf16 MFMA ----------------
// One wave per bf. LDS per wave (stride 80B rows, 32 bf16 used):
//   Ar rows 0-39 @0, Ai @3200, Br rows 0-47 @6400, Bi @10240, zero row @14080.
// A row m=(j=m>>3,c=m&7): w(t)*y_c(t-3-j).  B row n<40: y_c(t-3-j); n>=40: y_{n-40}(t).
// Re(R)=ArBr+AiBi; Im(R)=AiBr-ArBi (two accs, subtract at epilogue).
#define WBYTES 14160

__global__ __launch_bounds__(256) void rp_mfma_kernel(const float* __restrict__ mr,
                                                      const float* __restrict__ mi,
                                                      const float* __restrict__ W,
                                                      float2* __restrict__ Rout,
                                                      float2* __restrict__ Pout) {
    __shared__ __align__(16) unsigned char SH[4 * WBYTES];
    const int lane = threadIdx.x & 63;
    const int wid = threadIdx.x >> 6;
    const int bf = blockIdx.x * 4 + wid;
    unsigned char* base = SH + wid * WBYTES;

    const float* mrp = mr + (size_t)bf * C * T;
    const float* mip = mi + (size_t)bf * C * T;
    const float* Wp  = W  + (size_t)bf * T;

    // zero row (80 B)
    if (lane < 20) *(int*)(base + 14080 + lane * 4) = 0;

    const int q = lane >> 4, col = lane & 15;
    const unsigned char* aPtrR[3];
    const unsigned char* aPtrI[3];
    const unsigned char* bPtr[3];
#pragma unroll
    for (int mt = 0; mt < 3; ++mt) {
        int m = mt * 16 + col;
        aPtrR[mt] = base + ((m < K) ? m * 80 : 14080) + q * 16;
        aPtrI[mt] = base + ((m < K) ? 3200 + m * 80 : 14080) + q * 16;
    }
#pragma unroll
    for (int nt = 0; nt < 3; ++nt) {
        int n = nt * 16 + col;
        bPtr[nt] = base + 6400 + n * 80 + q * 16;   // Br; Bi at +3840
    }

    f32x4 accRe[3][3], accIr[3][3], accRi[3][3];
#pragma unroll
    for (int mt = 0; mt < 3; ++mt)
#pragma unroll
        for (int nt = 0; nt < 3; ++nt) {
            accRe[mt][nt] = (f32x4){0.f, 0.f, 0.f, 0.f};
            accIr[mt][nt] = (f32x4){0.f, 0.f, 0.f, 0.f};
            accRi[mt][nt] = (f32x4){0.f, 0.f, 0.f, 0.f};
        }

    for (int ks = 0; ks < 25; ++ks) {
        const int tb = ks * 32;
        // ---- stage this k-chunk (wave-private; DS ops in-order within wave) ----
#pragma unroll
        for (int it = 0; it < 6; ++it) {
            int idx = lane + it * 64;     // 384 tasks: (win 0..47) x (grp 0..7 of 4 t)
            int win = idx >> 3;
            int grp = idx & 7;
            int wo = win * 80 + grp * 8;
            if (win < K) {
                int j = win >> 3, c = win & 7;
                float4 w4 = *(const float4*)(Wp + tb + grp * 4);
                float wa[4] = {w4.x, w4.y, w4.z, w4.w};
                int tg = tb + grp * 4 - DELAY - j;
                bf16x4 ar, ai, br, bi;
#pragma unroll
                for (int e = 0; e < 4; ++e) {
                    int t_ = tg + e;
                    float vr = (t_ >= 0) ? mrp[c * T + t_] : 0.f;
                    float vi = (t_ >= 0) ? mip[c * T + t_] : 0.f;
                    ar[e] = (__bf16)(vr * wa[e]);
                    ai[e] = (__bf16)(vi * wa[e]);
                    br[e] = (__bf16)vr;
                    bi[e] = (__bf16)vi;
                }
                *(bf16x4*)(base + wo)         = ar;
                *(bf16x4*)(base + 3200 + wo)  = ai;
                *(bf16x4*)(base + 6400 + wo)  = br;
                *(bf16x4*)(base + 10240 + wo) = bi;
            } else {
                int c = win - K;
                int tg = tb + grp * 4;
                bf16x4 br, bi;
#pragma unroll
                for (int e = 0; e < 4; ++e) {
                    br[e] = (__bf16)mrp[c * T + tg + e];
                    bi[e] = (__bf16)mip[c * T + tg + e];
                }
                *(bf16x4*)(base + 6400 + wo)  = br;
                *(bf16x4*)(base + 10240 + wo) = bi;
            }
        }

        // ---- fragments + MFMA ----
        bf16x8 arf[3], aif[3], brf[3], bif[3];
#pragma unroll
        for (int mt = 0; mt < 3; ++mt) {
            arf[mt] = *(const bf16x8*)aPtrR[mt];
            aif[mt] = *(const bf16x8*)aPtrI[mt];
        }
#pragma unroll
        for (int nt = 0; nt < 3; ++nt) {
            brf[nt] = *(const bf16x8*)bPtr[nt];
            bif[nt] = *(const bf16x8*)(bPtr[nt] + 3840);
        }
#pragma unroll
        for (int mt = 0; mt < 3; ++mt)
#pragma unroll
            for (int nt = 0; nt < 3; ++nt) {
                accRe[mt][nt] = __builtin_amdgcn_mfma_f32_16x16x32_bf16(arf[mt], brf[nt], accRe[mt][nt], 0, 0, 0);
                accRe[mt][nt] = __builtin_amdgcn_mfma_f32_16x16x32_bf16(aif[mt], bif[nt], accRe[mt][nt], 0, 0, 0);
                accIr[mt][nt] = __builtin_amdgcn_mfma_f32_16x16x32_bf16(aif[mt], brf[nt], accIr[mt][nt], 0, 0, 0);
                accRi[mt][nt] = __builtin_amdgcn_mfma_f32_16x16x32_bf16(arf[mt], bif[nt], accRi[mt][nt], 0, 0, 0);
            }
    }

    // ---- epilogue: D row=(lane>>4)*4+r, col=lane&15 (m89-verified) ----
    float2* Rp = Rout + (size_t)bf * K * K;
    float2* Pp = Pout + (size_t)bf * K * C;
#pragma unroll
    for (int mt = 0; mt < 3; ++mt) {
#pragma unroll
        for (int r = 0; r < 4; ++r) {
            int m = mt * 16 + q * 4 + r;
            if (m < K) {
#pragma unroll
                for (int nt = 0; nt < 3; ++nt) {
                    int n = nt * 16 + col;
                    float re = accRe[mt][nt][r];
                    float im = accIr[mt][nt][r] - accRi[mt][nt][r];
                    if (n < K)
                        Rp[m * K + n] = make_float2(re, im);
                    else
                        Pp[m * C + (n - K)] = make_float2(re, im);
                }
            }
        }
    }
}

// ---------------- kernel 3: solve R G = P (complex LU, partial pivot) ----------------
__global__ __launch_bounds__(64) void solve_kernel(const float2* __restrict__ Rin,
                                                   const float2* __restrict__ Pin,
                                                   float2* __restrict__ Gout) {
    __shared__ float2 aug[K][NCOL + 1];
    int bf = blockIdx.x;
    int lane = threadIdx.x;

    for (int i = lane; i < K * K; i += 64) {
        int r = i / K, c2 = i % K;
        float2 v = Rin[(size_t)bf * K * K + i];
        if (r == c2) v.x += 1e-10f;
        aug[r][c2] = v;
    }
    for (int i = lane; i < K * C; i += 64)
        aug[i >> 3][K + (i & 7)] = Pin[(size_t)bf * K * C + i];
    __syncthreads();

    for (int j = 0; j < K; ++j) {
        float mag = -1.0f;
        int idx = lane;
        if (lane < K && lane >= j) {
            float2 v = aug[lane][j];
            mag = fabsf(v.x) + fabsf(v.y);
        }
        for (int off = 32; off; off >>= 1) {
            float om = __shfl_xor(mag, off);
            int oi = __shfl_xor(idx, off);
            if (om > mag || (om == mag && oi < idx)) { mag = om; idx = oi; }
        }
        int piv = idx;
        if (piv != j && lane < NCOL) {
            float2 tmp = aug[j][lane];
            aug[j][lane] = aug[piv][lane];
            aug[piv][lane] = tmp;
        }
        __syncthreads();
        float2 d = aug[j][j];
        float den = d.x * d.x + d.y * d.y;
        float2 invp = make_float2(d.x / den, -d.y / den);
        if (lane > j && lane < K) {
            float2 v = aug[lane][j];
            float2 l = make_float2(v.x * invp.x - v.y * invp.y,
                                   v.x * invp.y + v.y * invp.x);
            for (int n = j + 1; n < NCOL; ++n) {
                float2 u = aug[j][n];
                float2 a = aug[lane][n];
                a.x -= l.x * u.x - l.y * u.y;
                a.y -= l.x * u.y + l.y * u.x;
                aug[lane][n] = a;
            }
            aug[lane][j] = l;
        }
        __syncthreads();
    }

    for (int j = K - 1; j >= 0; --j) {
        float2 d = aug[j][j];
        float den = d.x * d.x + d.y * d.y;
        float2 invp = make_float2(d.x / den, -d.y / den);
        if (lane < C) {
            float2 v = aug[j][K + lane];
            aug[j][K + lane] = make_float2(v.x * invp.x - v.y * invp.y,
                                           v.x * invp.y + v.y * invp.x);
        }
        __syncthreads();
        for (int id = lane; id < j * C; id += 64) {
            int i = id >> 3, e = id & 7;
            float2 u = aug[i][j];
            float2 x = aug[j][K + e];
            float2 a = aug[i][K + e];
            a.x -= u.x * x.x - u.y * x.y;
            a.y -= u.x * x.y + u.y * x.x;
            aug[i][K + e] = a;
        }
        __syncthreads();
    }

    for (int i = lane; i < K * C; i += 64)
        Gout[(size_t)bf * K * C + i] = aug[i >> 3][K + (i & 7)];
}

// ---------------- kernel 4: X = Y - G^H Yt, mask, write out ----------------
#define PADT 801
__global__ __launch_bounds__(256) void x_kernel(const float* __restrict__ mr,
                                                const float* __restrict__ mi,
                                                const float2* __restrict__ Gin,
                                                const int* __restrict__ ilens,
                                                float2* __restrict__ out) {
    __shared__ float2 Ysh[C][PADT];
    __shared__ float2 Gsh[K][C];
    int bf = blockIdx.x;
    int b = bf / F;
    int tid = threadIdx.x;
    const float* mrp = mr + (size_t)bf * C * T;
    const float* mip = mi + (size_t)bf * C * T;
#pragma unroll
    for (int c = 0; c < C; ++c)
        for (int t = tid; t < T; t += 256)
            Ysh[c][t] = make_float2(mrp[c * T + t], mip[c * T + t]);
    for (int i = tid; i < K * C; i += 256)
        Gsh[i >> 3][i & 7] = Gin[(size_t)bf * K * C + i];
    __syncthreads();

    int len = ilens[b];

    float2 acc[4][C];
#pragma unroll
    for (int it = 0; it < 4; ++it) {
        int t = tid + it * 256;
#pragma unroll
        for (int e = 0; e < C; ++e)
            acc[it][e] = (t < T) ? Ysh[e][t] : make_float2(0.f, 0.f);
    }

#pragma unroll
    for (int k = 0; k < TAPS; ++k) {
#pragma unroll
        for (int c = 0; c < C; ++c) {
            int a = k * C + c;
            float2 g[C];
#pragma unroll
            for (int e = 0; e < C; ++e) g[e] = Gsh[a][e];
#pragma unroll
            for (int it = 0; it < 4; ++it) {
                int t = tid + it * 256;
                int tsrc = t - DELAY - k;
                if (t < T && tsrc >= 0) {
                    float2 yt = Ysh[c][tsrc];
#pragma unroll
                    for (int e = 0; e < C; ++e) {
                        acc[it][e].x = fmaf(-g[e].x, yt.x, acc[it][e].x);
                        acc[it][e].x = fmaf(-g[e].y, yt.y, acc[it][e].x);
                        acc[it][e].y = fmaf(-g[e].x, yt.y, acc[it][e].y);
                        acc[it][e].y = fmaf(g[e].y, yt.x, acc[it][e].y);
                    }
                }
            }
        }
    }

#pragma unroll
    for (int it = 0; it < 4; ++it) {
        int t = tid + it * 256;
        if (t < T) {
            bool ok = (t < len);
#pragma unroll
            for (int e = 0; e < C; ++e) {
                float2 v = ok ? acc[it][e] : make_float2(0.f, 0.f);
                out[((size_t)bf * C + e) * T + t] = v;
            }
        }
    }
}

extern "C" void kernel_launch(void* const* d_in, const int* in_sizes, int n_in,
                              void* d_out, int out_size, void* d_ws, size_t ws_size,
                              hipStream_t stream) {
    const float* sep_r = (const float*)d_in[0];
    const float* sep_i = (const float*)d_in[1];
    const float* mix_r = (const float*)d_in[2];
    const float* mix_i = (const float*)d_in[3];
    const int* ilens   = (const int*)d_in[4];

    float* ws = (float*)d_ws;
    float* W = ws;                                        // BF*T floats
    float2* Rws = (float2*)(ws + (size_t)BF * T);         // BF*K*K float2
    float2* Gws = Rws + (size_t)BF * K * K;               // BF*K*C float2 (P then G in-place)

    power_kernel<<<BF, 256, 0, stream>>>(sep_r, sep_i, W);
    rp_mfma_kernel<<<BF / 4, 256, 0, stream>>>(mix_r, mix_i, W, Rws, Gws);
    solve_kernel<<<BF, 64, 0, stream>>>(Rws, Gws, Gws);
    x_kernel<<<BF, 256, 0, stream>>>(mix_r, mix_i, Gws, ilens, (float2*)d_out);
}

// Round 6
// 362.101 us; speedup vs baseline: 4.0188x; 1.3403x over previous
//
#include <hip/hip_runtime.h>

#define B 8
#define F 257
#define C 8
#define T 800
#define TAPS 5
#define DELAY 3
#define K 40         // TAPS*C
#define NCOL 48      // K + C
#define T0 7         // DELAY + TAPS - 1
#define BF (B*F)     // 2056

typedef __bf16 bf16x8 __attribute__((ext_vector_type(8)));
typedef __bf16 bf16x4 __attribute__((ext_vector_type(4)));
typedef float f32x4 __attribute__((ext_vector_type(4)));

// ---------------- kernel 1: sqrt inverse power weights (0 for t<T0) ----------------
__global__ __launch_bounds__(256) void power_kernel(const float* __restrict__ sr,
                                                    const float* __restrict__ si,
                                                    float* __restrict__ W) {
    int bf = blockIdx.x;
    const float* srp = sr + (size_t)bf * C * T;
    const float* sip = si + (size_t)bf * C * T;
    int t0 = threadIdx.x * 4;
    if (t0 < T) {
        float s[4] = {0.f, 0.f, 0.f, 0.f};
#pragma unroll
        for (int c = 0; c < C; ++c) {
            float4 a = *(const float4*)(srp + c * T + t0);
            float4 b = *(const float4*)(sip + c * T + t0);
            s[0] = fmaf(a.x, a.x, fmaf(b.x, b.x, s[0]));
            s[1] = fmaf(a.y, a.y, fmaf(b.y, b.y, s[1]));
            s[2] = fmaf(a.z, a.z, fmaf(b.z, b.z, s[2]));
            s[3] = fmaf(a.w, a.w, fmaf(b.w, b.w, s[3]));
        }
        float4 w;
        float* wp = (float*)&w;
#pragma unroll
        for (int e = 0; e < 4; ++e) {
            float v = fmaxf(s[e] * (1.0f / C), 1e-7f);
            wp[e] = (t0 + e < T0) ? 0.f : rsqrtf(v);   // sqrt(1/power)
        }
        *(float4*)(W + (size_t)bf * T + t0) = w;
    }
}

// ---------------- kernel 2: R,P via bf16 MFMA, sqrt(w)-symmetrized Gram ----------------
// One wave per bf, 4 waves/block, wave-private LDS, NO barriers.
// Z rows (48): r<40: (j=r>>3,c=r&7): sqrt(w(t))*y_c(t-3-j); r>=40: sqrt(w(t))*y_{r-40}(t).
// R = Z[0:40] Z[0:40]^H, P = Z[0:40] Z[40:48]^H. Hermitian: 6 tile-pairs, mirror at epilogue.
// Per-wave LDS layout (WB=10624 B):
//   Zr @0 (48 rows x 80B), Zi @3840, scratch re @7680 (8x44 f32), im @9088, w @10496 (32 f32)
#define WB 10624

__global__ __launch_bounds__(256, 3) void rp_mfma_kernel(const float* __restrict__ mr,
                                                         const float* __restrict__ mi,
                                                         const float* __restrict__ W,
                                                         float2* __restrict__ Rout,
                                                         float2* __restrict__ Pout) {
    __shared__ __align__(16) unsigned char SH[4 * WB];
    const int lane = threadIdx.x & 63;
    const int wid = threadIdx.x >> 6;
    const int bf = blockIdx.x * 4 + wid;
    unsigned char* base = SH + wid * WB;
    float* sre = (float*)(base + 7680);
    float* sim_ = (float*)(base + 9088);
    float* wsh = (float*)(base + 10496);

    const float* mrp = mr + (size_t)bf * C * T;
    const float* mip = mi + (size_t)bf * C * T;
    const float* Wp  = W  + (size_t)bf * T;

    const int q = lane >> 4, col = lane & 15;
    const int pc = lane >> 3, pg = lane & 7;     // phase-B task: channel, 4t-group

    const int PM[6] = {0, 0, 0, 1, 1, 2};
    const int PN[6] = {0, 1, 2, 1, 2, 2};

    f32x4 accRe[6], accIr[6], accRi[6];
#pragma unroll
    for (int p = 0; p < 6; ++p) {
        accRe[p] = (f32x4){0.f, 0.f, 0.f, 0.f};
        accIr[p] = (f32x4){0.f, 0.f, 0.f, 0.f};
        accRi[p] = (f32x4){0.f, 0.f, 0.f, 0.f};
    }

    for (int ks = 0; ks < 25; ++ks) {
        const int tb = ks * 32;

        // ---- Phase A: vectorized global -> fp32 LDS scratch ----
#pragma unroll
        for (int it = 0; it < 3; ++it) {
            int task = lane + it * 64;
            if (task < 160) {
                int pl = task / 80;
                int rem = task - pl * 80;
                int c = rem / 10, grp = rem - c * 10;
                int tg = tb - 8 + grp * 4;
                const float* srcp = pl ? mip : mrp;
                float4 v = make_float4(0.f, 0.f, 0.f, 0.f);
                if (tg >= 0) v = *(const float4*)(srcp + c * T + tg);
                *(float4*)((pl ? sim_ : sre) + c * 44 + grp * 4) = v;
            } else if (task < 168) {
                int grp = task - 160;
                *(float4*)(wsh + grp * 4) = *(const float4*)(Wp + tb + grp * 4);
            }
        }

        // ---- Phase B: build 6 shift-variant bf16 rows from scratch ----
        {
            float yre[12], yim[12];
            int ybase = pc * 44 + pg * 4;
#pragma unroll
            for (int i = 1; i <= 11; ++i) {
                yre[i] = sre[ybase + i];
                yim[i] = sim_[ybase + i];
            }
            float4 w4 = *(const float4*)(wsh + pg * 4);
            float wv[4] = {w4.x, w4.y, w4.z, w4.w};
#pragma unroll
            for (int v = 0; v < 6; ++v) {
                int row = (v < 5) ? (v * 8 + pc) : (40 + pc);
                int off = (v < 5) ? (5 - v) : 8;
                bf16x4 zr, zi;
#pragma unroll
                for (int e = 0; e < 4; ++e) {
                    zr[e] = (__bf16)(wv[e] * yre[off + e]);
                    zi[e] = (__bf16)(wv[e] * yim[off + e]);
                }
                *(bf16x4*)(base + row * 80 + pg * 8) = zr;
                *(bf16x4*)(base + 3840 + row * 80 + pg * 8) = zi;
            }
        }

        // ---- fragments (shared A/B operand) + 24 MFMA ----
        bf16x8 fr[3], fi[3];
#pragma unroll
        for (int X = 0; X < 3; ++X) {
            fr[X] = *(const bf16x8*)(base + (X * 16 + col) * 80 + q * 16);
            fi[X] = *(const bf16x8*)(base + 3840 + (X * 16 + col) * 80 + q * 16);
        }
#pragma unroll
        for (int p = 0; p < 6; ++p) {
            int mt = PM[p], nt = PN[p];
            accRe[p] = __builtin_amdgcn_mfma_f32_16x16x32_bf16(fr[mt], fr[nt], accRe[p], 0, 0, 0);
            accRe[p] = __builtin_amdgcn_mfma_f32_16x16x32_bf16(fi[mt], fi[nt], accRe[p], 0, 0, 0);
            accIr[p] = __builtin_amdgcn_mfma_f32_16x16x32_bf16(fi[mt], fr[nt], accIr[p], 0, 0, 0);
            accRi[p] = __builtin_amdgcn_mfma_f32_16x16x32_bf16(fr[mt], fi[nt], accRi[p], 0, 0, 0);
        }
    }

    // ---- epilogue: D row=(lane>>4)*4+reg, col=lane&15 (m89); Hermitian mirror ----
    float2* Rp = Rout + (size_t)bf * K * K;
    float2* Pp = Pout + (size_t)bf * K * C;
#pragma unroll
    for (int p = 0; p < 6; ++p) {
        int mt = PM[p], nt = PN[p];
#pragma unroll
        for (int r = 0; r < 4; ++r) {
            int m = mt * 16 + q * 4 + r;
            int n = nt * 16 + col;
            float re = accRe[p][r];
            float im = accIr[p][r] - accRi[p][r];
            if (m < K) {
                if (n < K) Rp[m * K + n] = make_float2(re, im);
                else       Pp[m * C + (n - K)] = make_float2(re, im);
            }
            if (mt != nt && m < K && n < K)
                Rp[n * K + m] = make_float2(re, -im);
        }
    }
}

// ---------------- kernel 3: solve R G = P (complex LU, partial pivot) ----------------
__global__ __launch_bounds__(64) void solve_kernel(const float2* __restrict__ Rin,
                                                   const float2* __restrict__ Pin,
                                                   float2* __restrict__ Gout) {
    __shared__ float2 aug[K][NCOL + 1];
    int bf = blockIdx.x;
    int lane = threadIdx.x;

    for (int i = lane; i < K * K; i += 64) {
        int r = i / K, c2 = i % K;
        float2 v = Rin[(size_t)bf * K * K + i];
        if (r == c2) v.x += 1e-10f;
        aug[r][c2] = v;
    }
    for (int i = lane; i < K * C; i += 64)
        aug[i >> 3][K + (i & 7)] = Pin[(size_t)bf * K * C + i];
    __syncthreads();

    for (int j = 0; j < K; ++j) {
        float mag = -1.0f;
        int idx = lane;
        if (lane < K && lane >= j) {
            float2 v = aug[lane][j];
            mag = fabsf(v.x) + fabsf(v.y);
        }
        for (int off = 32; off; off >>= 1) {
            float om = __shfl_xor(mag, off);
            int oi = __shfl_xor(idx, off);
            if (om > mag || (om == mag && oi < idx)) { mag = om; idx = oi; }
        }
        int piv = idx;
        if (piv != j && lane < NCOL) {
            float2 tmp = aug[j][lane];
            aug[j][lane] = aug[piv][lane];
            aug[piv][lane] = tmp;
        }
        __syncthreads();
        float2 d = aug[j][j];
        float den = d.x * d.x + d.y * d.y;
        float2 invp = make_float2(d.x / den, -d.y / den);
        if (lane > j && lane < K) {
            float2 v = aug[lane][j];
            float2 l = make_float2(v.x * invp.x - v.y * invp.y,
                                   v.x * invp.y + v.y * invp.x);
            for (int n = j + 1; n < NCOL; ++n) {
                float2 u = aug[j][n];
                float2 a = aug[lane][n];
                a.x -= l.x * u.x - l.y * u.y;
                a.y -= l.x * u.y + l.y * u.x;
                aug[lane][n] = a;
            }
            aug[lane][j] = l;
        }
        __syncthreads();
    }

    for (int j = K - 1; j >= 0; --j) {
        float2 d = aug[j][j];
        float den = d.x * d.x + d.y * d.y;
        float2 invp = make_float2(d.x / den, -d.y / den);
        if (lane < C) {
            float2 v = aug[j][K + lane];
            aug[j][K + lane] = make_float2(v.x * invp.x - v.y * invp.y,
                                           v.x * invp.y + v.y * invp.x);
        }
        __syncthreads();
        for (int id = lane; id < j * C; id += 64) {
            int i = id >> 3, e = id & 7;
            float2 u = aug[i][j];
            float2 x = aug[j][K + e];
            float2 a = aug[i][K + e];
            a.x -= u.x * x.x - u.y * x.y;
            a.y -= u.x * x.y + u.y * x.x;
            aug[i][K + e] = a;
        }
        __syncthreads();
    }

    for (int i = lane; i < K * C; i += 64)
        Gout[(size_t)bf * K * C + i] = aug[i >> 3][K + (i & 7)];
}

// ---------------- kernel 4: X = Y - G^H Yt, mask, write out ----------------
#define PADT 801
__global__ __launch_bounds__(256) void x_kernel(const float* __restrict__ mr,
                                                const float* __restrict__ mi,
                                                const float2* __restrict__ Gin,
                                                const int* __restrict__ ilens,
                                                float2* __restrict__ out) {
    __shared__ float2 Ysh[C][PADT];
    __shared__ float2 Gsh[K][C];
    int bf = blockIdx.x;
    int b = bf / F;
    int tid = threadIdx.x;
    const float* mrp = mr + (size_t)bf * C * T;
    const float* mip = mi + (size_t)bf * C * T;
#pragma unroll
    for (int c = 0; c < C; ++c)
        for (int t = tid; t < T; t += 256)
            Ysh[c][t] = make_float2(mrp[c * T + t], mip[c * T + t]);
    for (int i = tid; i < K * C; i += 256)
        Gsh[i >> 3][i & 7] = Gin[(size_t)bf * K * C + i];
    __syncthreads();

    int len = ilens[b];

    float2 acc[4][C];
#pragma unroll
    for (int it = 0; it < 4; ++it) {
        int t = tid + it * 256;
#pragma unroll
        for (int e = 0; e < C; ++e)
            acc[it][e] = (t < T) ? Ysh[e][t] : make_float2(0.f, 0.f);
    }

#pragma unroll
    for (int k = 0; k < TAPS; ++k) {
#pragma unroll
        for (int c = 0; c < C; ++c) {
            int a = k * C + c;
            float2 g[C];
#pragma unroll
            for (int e = 0; e < C; ++e) g[e] = Gsh[a][e];
#pragma unroll
            for (int it = 0; it < 4; ++it) {
                int t = tid + it * 256;
                int tsrc = t - DELAY - k;
                if (t < T && tsrc >= 0) {
                    float2 yt = Ysh[c][tsrc];
#pragma unroll
                    for (int e = 0; e < C; ++e) {
                        acc[it][e].x = fmaf(-g[e].x, yt.x, acc[it][e].x);
                        acc[it][e].x = fmaf(-g[e].y, yt.y, acc[it][e].x);
                        acc[it][e].y = fmaf(-g[e].x, yt.y, acc[it][e].y);
                        acc[it][e].y = fmaf(g[e].y, yt.x, acc[it][e].y);
                    }
                }
            }
        }
    }

#pragma unroll
    for (int it = 0; it < 4; ++it) {
        int t = tid + it * 256;
        if (t < T) {
            bool ok = (t < len);
#pragma unroll
            for (int e = 0; e < C; ++e) {
                float2 v = ok ? acc[it][e] : make_float2(0.f, 0.f);
                out[((size_t)bf * C + e) * T + t] = v;
            }
        }
    }
}

extern "C" void kernel_launch(void* const* d_in, const int* in_sizes, int n_in,
                              void* d_out, int out_size, void* d_ws, size_t ws_size,
                              hipStream_t stream) {
    const float* sep_r = (const float*)d_in[0];
    const float* sep_i = (const float*)d_in[1];
    const float* mix_r = (const float*)d_in[2];
    const float* mix_i = (const float*)d_in[3];
    const int* ilens   = (const int*)d_in[4];

    float* ws = (float*)d_ws;
    float* W = ws;                                        // BF*T floats
    float2* Rws = (float2*)(ws + (size_t)BF * T);         // BF*K*K float2
    float2* Gws = Rws + (size_t)BF * K * K;               // BF*K*C float2 (P then G in-place)

    power_kernel<<<BF, 256, 0, stream>>>(sep_r, sep_i, W);
    rp_mfma_kernel<<<BF / 4, 256, 0, stream>>>(mix_r, mix_i, W, Rws, Gws);
    solve_kernel<<<BF, 64, 0, stream>>>(Rws, Gws, Gws);
    x_kernel<<<BF, 256, 0, stream>>>(mix_r, mix_i, Gws, ilens, (float2*)d_out);
}